// Round 3
// baseline (268.755 us; speedup 1.0000x reference)
//
#include <hip/hip_runtime.h>
#include <math.h>

#define NT 1024
#define KSEL 100
#define NWAVE 16

// ws layout (floats):
//   Ct  [3][256][32]  at      0  (24576)   Ct[l][i][h] = sum_j w1[h,j]*W[j,i]
//   W0T [256][256]    at  24576  (65536)   W0T[c*256+i] = W0[i*256+c]
//   W1T [256][256]    at  90112  (65536)
//   W2T [256][128]    at 155648  (32768)   W2T[c*128+o] = W2[o*256+c]
#define WS_FLOATS 188416

// ---------- order-preserving float <-> uint key ----------
__device__ __forceinline__ unsigned fkey(float f) {
  unsigned u = __float_as_uint(f);
  return (u & 0x80000000u) ? ~u : (u | 0x80000000u);
}
__device__ __forceinline__ float unfkey(unsigned k) {
  return __uint_as_float((k & 0x80000000u) ? (k & 0x7FFFFFFFu) : ~k);
}
__device__ __forceinline__ unsigned long long lower_mask(int lane) {
  return lane ? (~0ull >> (64 - lane)) : 0ull;
}

// wave-aggregated histogram add: match_any via 8 ballots, leader adds popcount
__device__ __forceinline__ void hist_agg(unsigned* histw, unsigned digit, bool cand, int lane) {
  unsigned long long m = __ballot(cand);
  if (m == 0ull) return;                      // wave-uniform early-out
  unsigned long long match = m;
  #pragma unroll
  for (int bit = 0; bit < 8; ++bit) {
    unsigned long long bb = __ballot(cand && ((digit >> bit) & 1u));
    match &= ((digit >> bit) & 1u) ? bb : ~bb;
  }
  if (cand && (match & lower_mask(lane)) == 0ull)
    atomicAdd(&histw[digit], (unsigned)__popcll(match));
}

// recompute the path value s for element id e (e == p*256+i == JAX path index)
template<int NE>
__device__ __forceinline__ float recompute_s(int e, int b,
    const float* __restrict__ x, const float* __restrict__ wt,
    const float* __restrict__ Wprev, const int* path_col, const float* path_t)
{
  int i = e & 255;
  if (NE == 1) return x[b * 256 + i];
  int p = e >> 8;
  float w = wt ? wt[path_col[p] * 256 + i] : Wprev[i * 256 + path_col[p]];
  return tanhf(w * path_t[p]);
}

// ---------- exact top-100 radix select ----------
// NE==1 : 256 real elements (threads t<256), e = t  (others hold -inf)
// NE==25: 25600 elements, e = j*NT + t  (p = e>>8, i = e&255)
// prefix_p/krem_p/nsel_p/ntie_p must be pre-initialized (0,KSEL,0,0) before entry.
template<int NE>
__device__ __forceinline__ void topk_sel(
    const float (&sc)[25], int b, int t,
    const float* __restrict__ x, const float* __restrict__ wt,
    const float* __restrict__ Wprev,
    const int* path_col, const float* path_t,
    unsigned* hist,                      // [NWAVE*256] per-wave copies
    int* sel_col, float* sel_s, float* sel_sc,
    unsigned* tieq,
    int* nsel_p, int* ntie_p, unsigned* prefix_p, int* krem_p)
{
  const int lane = t & 63;
  unsigned* histw = hist + ((t >> 6) << 8);

  #pragma unroll
  for (int pass = 0; pass < 4; ++pass) {
    // zero own wave's copy (wave-private; no barrier needed)
    {
      const int l4 = lane << 2;
      histw[l4] = 0u; histw[l4 + 1] = 0u; histw[l4 + 2] = 0u; histw[l4 + 3] = 0u;
    }
    const unsigned pref = *prefix_p;
    const int shift = 24 - 8 * pass;
    #pragma unroll
    for (int j = 0; j < NE; ++j) {
      unsigned key = fkey(sc[j]);
      bool cand = (pass == 0) || ((key >> (shift + 8)) == pref);
      hist_agg(histw, (key >> shift) & 255u, cand, lane);
    }
    __syncthreads();
    if (t < 64) {
      const int l4 = t << 2;
      unsigned h0 = 0, h1 = 0, h2 = 0, h3 = 0;
      #pragma unroll
      for (int k = 0; k < NWAVE; ++k) {
        const uint4 v = *(const uint4*)&hist[(k << 8) + l4];
        h0 += v.x; h1 += v.y; h2 += v.z; h3 += v.w;
      }
      unsigned csum = h0 + h1 + h2 + h3;
      unsigned S = csum;                       // inclusive suffix over lane chunk sums
      #pragma unroll
      for (int off = 1; off < 64; off <<= 1) {
        unsigned v = __shfl_down(S, off, 64);
        if (t + off < 64) S += v;
      }
      unsigned tail = S - csum;
      unsigned s3 = tail + h3;
      unsigned s2 = s3 + h2;
      unsigned s1 = s2 + h1;
      unsigned s0v = s1 + h0;
      int krem = *krem_p;
      int ld = -1; unsigned sfx = 0, hd = 0;
      if      ((int)s3  >= krem) { ld = l4+3; sfx = s3;  hd = h3; }
      else if ((int)s2  >= krem) { ld = l4+2; sfx = s2;  hd = h2; }
      else if ((int)s1  >= krem) { ld = l4+1; sfx = s1;  hd = h1; }
      else if ((int)s0v >= krem) { ld = l4+0; sfx = s0v; hd = h0; }
      int gd = ld;
      #pragma unroll
      for (int off = 32; off >= 1; off >>= 1) {
        int v = __shfl_down(gd, off, 64);
        if (t + off < 64) gd = (v > gd) ? v : gd;
      }
      gd = __shfl(gd, 0, 64);
      if (ld == gd && ld >= 0) {               // unique owner lane
        *krem_p = krem - (int)(sfx - hd);
        *prefix_p = (pref << 8) | (unsigned)gd;
      }
    }
    __syncthreads();
  }

  const unsigned T = *prefix_p;                // exact key of the 100th-largest score

  #pragma unroll
  for (int j = 0; j < NE; ++j) {
    unsigned key = fkey(sc[j]);
    int e = (NE == 1) ? t : (j * NT + t);
    bool selp = key > T;
    unsigned long long m = __ballot(selp);
    if (m) {
      int leader = __ffsll((unsigned long long)m) - 1;
      int base = 0;
      if (selp && (m & lower_mask(lane)) == 0ull)
        base = atomicAdd(nsel_p, (int)__popcll(m));
      base = __shfl(base, leader, 64);
      if (selp) {
        int slot = base + (int)__popcll(m & lower_mask(lane));
        sel_col[slot] = e & 255;
        sel_s[slot] = recompute_s<NE>(e, b, x, wt, Wprev, path_col, path_t);
        sel_sc[slot] = sc[j];
      }
    }
    bool tiep = (key == T);
    if (__ballot(tiep)) {
      if (tiep) {
        int tp = atomicAdd(ntie_p, 1);
        if (tp < 128) tieq[tp] = (unsigned)e;
      }
    }
  }
  __syncthreads();

  if (t < 64) {                                // wave 0 handles ties (usually 1 element)
    if (t == 0) {                              // ascending element id (JAX: lowest index first)
      int m = *ntie_p; if (m > 128) m = 128;
      for (int a = 1; a < m; ++a) {
        unsigned v = tieq[a]; int c = a - 1;
        while (c >= 0 && tieq[c] > v) { tieq[c + 1] = tieq[c]; --c; }
        tieq[c + 1] = v;
      }
    }
    const int G = *nsel_p;
    const int kt = KSEL - G;
    for (int q = t; q < kt; q += 64) {
      int e = (int)tieq[q];
      sel_col[G + q] = e & 255;
      sel_s[G + q] = recompute_s<NE>(e, b, x, wt, Wprev, path_col, path_t);
      sel_sc[G + q] = unfkey(T);
    }
  }
  __syncthreads();
}

// ---------- kernel 1: Ct + transposed weights into ws ----------
__global__ void pqn_precompute(
    const float* __restrict__ W0, const float* __restrict__ W1, const float* __restrict__ W2,
    const float* __restrict__ s0w1, const float* __restrict__ s1w1, const float* __restrict__ s2w1,
    float* __restrict__ ws)
{
  int id = blockIdx.x * 256 + threadIdx.x;
  if (id < 24576) {
    int l = id >> 13, r = id & 8191;
    int i = r >> 5, h = r & 31;
    const float* W  = (l == 0) ? W0 : (l == 1) ? W1 : W2;
    const float* w1 = (l == 0) ? s0w1 : (l == 1) ? s1w1 : s2w1;
    const int Fout = (l == 2) ? 128 : 256;
    float acc = 0.f;
    for (int j = 0; j < Fout; ++j)
      acc = fmaf(w1[h * Fout + j], W[j * 256 + i], acc);
    ws[l * 8192 + i * 32 + h] = acc;
  } else if (id < 90112) {
    int k = id - 24576; int c = k >> 8, i = k & 255;
    ws[24576 + k] = W0[i * 256 + c];
  } else if (id < 155648) {
    int k = id - 90112; int c = k >> 8, i = k & 255;
    ws[90112 + k] = W1[i * 256 + c];
  } else if (id < 188416) {
    int k = id - 155648; int c = k >> 7, o = k & 127;
    ws[155648 + k] = W2[o * 256 + c];
  }
}

// ---------- kernel 2: one block per batch ----------
__global__ __launch_bounds__(NT) void pqn_main(
    const float* __restrict__ x,
    const float* __restrict__ W0, const float* __restrict__ W1, const float* __restrict__ W2,
    const float* __restrict__ s0w1, const float* __restrict__ s1w1, const float* __restrict__ s2w1,
    const float* __restrict__ s0b1, const float* __restrict__ s1b1, const float* __restrict__ s2b1,
    const float* __restrict__ s0w2, const float* __restrict__ s1w2, const float* __restrict__ s2w2,
    const float* __restrict__ s0b2, const float* __restrict__ s1b2, const float* __restrict__ s2b2,
    const float* __restrict__ Ctg,   // null or [3][256][32]
    const float* __restrict__ Wtb,   // null or {W0T,W1T,W2T}
    float* __restrict__ out)
{
  __shared__ float Cl[8192];                    // fallback C (i-major), 32 KB
  __shared__ float A[256], Bc[256];
  __shared__ unsigned hist[NWAVE * 256];        // per-wave histogram copies, 16 KB
  __shared__ int   path_col[KSEL]; __shared__ float path_t[KSEL];
  __shared__ int   sel_col[KSEL];  __shared__ float sel_s[KSEL]; __shared__ float sel_sc[KSEL];
  __shared__ unsigned tieq[128];
  __shared__ int nsel_s, ntie_s, krem_s; __shared__ unsigned prefix_s;
  __shared__ int bz_s; __shared__ float b2_sh;
  __shared__ float wts[KSEL]; __shared__ float red[4];

  const int b = blockIdx.x;
  const int t = threadIdx.x;
  const bool useC  = (Ctg != nullptr);
  const bool useWT = (Wtb != nullptr);
  const float* W0T = useWT ? Wtb : nullptr;
  const float* W1T = useWT ? (Wtb + 65536) : nullptr;
  const float* W2T = useWT ? (Wtb + 131072) : nullptr;

  float sc[25];

  for (int l = 0; l < 3; ++l) {
    const float* w1 = (l == 0) ? s0w1 : (l == 1) ? s1w1 : s2w1;
    const float* b1 = (l == 0) ? s0b1 : (l == 1) ? s1b1 : s2b1;
    const float* w2 = (l == 0) ? s0w2 : (l == 1) ? s1w2 : s2w2;
    const float* b2 = (l == 0) ? s0b2 : (l == 1) ? s1b2 : s2b2;
    const float* Wl = (l == 0) ? W0 : (l == 1) ? W1 : W2;
    const float* Wprev = (l == 1) ? W0 : W1;
    const float* WTprev = (l == 1) ? W0T : W1T;
    const int Fout = (l == 2) ? 128 : 256;

    const float* ct;
    if (useC) {
      ct = Ctg + l * 8192;                     // i-major [256][32]
    } else {
      for (int id = t; id < 8192; id += NT) {
        int i = id >> 5, h = id & 31;
        float acc = 0.f;
        for (int j = 0; j < Fout; ++j) acc = fmaf(w1[h * Fout + j], Wl[j * 256 + i], acc);
        Cl[id] = acc;
      }
      ct = Cl;
      __syncthreads();
    }

    // scorer coefficients: score(s,i) = s * (s>0 ? A_i : B_i) + b2  (valid when b1==0)
    if (t < 256) {
      float a = 0.f, bn = 0.f;
      #pragma unroll
      for (int h = 0; h < 32; ++h) {
        float c = ct[t * 32 + h];
        float wc = w2[h] * c;
        if (c > 0.f) a += wc; else if (c < 0.f) bn += wc;
      }
      A[t] = a; Bc[t] = bn;
    }
    if (t == 0) {
      b2_sh = b2[0];
      int z = 1;
      for (int h = 0; h < 32; ++h) if (b1[h] != 0.f) z = 0;
      bz_s = z;
      prefix_s = 0u; krem_s = KSEL; nsel_s = 0; ntie_s = 0;   // select-state init folded in
    }
    __syncthreads();
    const bool  bz  = (bz_s != 0);
    const float b2v = b2_sh;

    if (l == 0) {
      float v = -INFINITY;
      if (t < 256) {
        float s = x[b * 256 + t];
        if (bz) v = s * (s > 0.f ? A[t] : Bc[t]) + b2v;
        else {
          v = b2v;
          for (int h = 0; h < 32; ++h)
            v += w2[h] * fmaxf(fmaf(s, ct[t * 32 + h], b1[h]), 0.f);
        }
      }
      sc[0] = v;
      topk_sel<1>(sc, b, t, x, nullptr, nullptr, path_col, path_t, hist,
                  sel_col, sel_s, sel_sc, tieq, &nsel_s, &ntie_s, &prefix_s, &krem_s);
    } else {
      #pragma unroll
      for (int j = 0; j < 25; ++j) {
        int e = j * NT + t;
        int i = e & 255, p = e >> 8;              // p wave-uniform, i lane-consecutive
        float w = useWT ? WTprev[path_col[p] * 256 + i]      // coalesced
                        : Wprev[i * 256 + path_col[p]];       // fallback scattered
        float s = tanhf(w * path_t[p]);
        float v;
        if (bz) v = s * (s > 0.f ? A[i] : Bc[i]) + b2v;
        else {
          v = b2v;
          for (int h = 0; h < 32; ++h)
            v += w2[h] * fmaxf(fmaf(s, ct[i * 32 + h], b1[h]), 0.f);
        }
        sc[j] = v;
      }
      topk_sel<25>(sc, b, t, x, WTprev, Wprev, path_col, path_t, hist,
                   sel_col, sel_s, sel_sc, tieq, &nsel_s, &ntie_s, &prefix_s, &krem_s);
    }

    if (l < 2) {
      if (t < KSEL) { path_col[t] = sel_col[t]; path_t[t] = sel_s[t]; }
      // visibility guaranteed by next layer's setup __syncthreads
    }
  }

  // ---------- epilogue: softmax over final scores, weighted column sum ----------
  {
    float v = (t < KSEL) ? sel_sc[t] : -INFINITY;
    if (t < 128) {
      #pragma unroll
      for (int off = 32; off >= 1; off >>= 1) v = fmaxf(v, __shfl_xor(v, off, 64));
      if ((t & 63) == 0) red[t >> 6] = v;
    }
    __syncthreads();
    const float m = fmaxf(red[0], red[1]);
    if (t < KSEL) wts[t] = expf(sel_sc[t] - m);
    __syncthreads();
    float sv = (t < KSEL) ? wts[t] : 0.f;
    if (t < 128) {
      #pragma unroll
      for (int off = 32; off >= 1; off >>= 1) sv += __shfl_xor(sv, off, 64);
      if ((t & 63) == 0) red[2 + (t >> 6)] = sv;
    }
    __syncthreads();
    const float ssum = red[2] + red[3];
    if (t < KSEL) wts[t] = wts[t] * sel_s[t] / ssum;   // coef_p = softmax_p * s_p
    __syncthreads();
    if (t < 128) {
      float acc = 0.f;
      if (useWT) {
        for (int p = 0; p < KSEL; ++p)
          acc = fmaf(W2T[sel_col[p] * 128 + t], wts[p], acc);   // coalesced
      } else {
        for (int p = 0; p < KSEL; ++p)
          acc = fmaf(W2[t * 256 + sel_col[p]], wts[p], acc);
      }
      out[b * 128 + t] = acc;
    }
  }
}

extern "C" void kernel_launch(void* const* d_in, const int* in_sizes, int n_in,
                              void* d_out, int out_size, void* d_ws, size_t ws_size,
                              hipStream_t stream) {
  const float* x    = (const float*)d_in[0];
  const float* W0   = (const float*)d_in[1];
  const float* s0w1 = (const float*)d_in[2];
  const float* s0b1 = (const float*)d_in[3];
  const float* s0w2 = (const float*)d_in[4];
  const float* s0b2 = (const float*)d_in[5];
  const float* W1   = (const float*)d_in[6];
  const float* s1w1 = (const float*)d_in[7];
  const float* s1b1 = (const float*)d_in[8];
  const float* s1w2 = (const float*)d_in[9];
  const float* s1b2 = (const float*)d_in[10];
  const float* W2   = (const float*)d_in[11];
  const float* s2w1 = (const float*)d_in[12];
  const float* s2b1 = (const float*)d_in[13];
  const float* s2w2 = (const float*)d_in[14];
  const float* s2b2 = (const float*)d_in[15];
  float* out = (float*)d_out;
  float* ws  = (float*)d_ws;

  const bool fullWs = ws_size >= (size_t)WS_FLOATS * sizeof(float);
  const bool cOnly  = !fullWs && ws_size >= (size_t)24576 * sizeof(float);

  const float* Ctg = nullptr; const float* Wtb = nullptr;
  if (fullWs) {
    pqn_precompute<<<736, 256, 0, stream>>>(W0, W1, W2, s0w1, s1w1, s2w1, ws);
    Ctg = ws; Wtb = ws + 24576;
  } else if (cOnly) {
    pqn_precompute<<<96, 256, 0, stream>>>(W0, W1, W2, s0w1, s1w1, s2w1, ws);
    Ctg = ws;
  }

  pqn_main<<<16, NT, 0, stream>>>(x, W0, W1, W2,
                                  s0w1, s1w1, s2w1,
                                  s0b1, s1b1, s2b1,
                                  s0w2, s1w2, s2w2,
                                  s0b2, s1b2, s2b2,
                                  Ctg, Wtb, out);
}

// Round 4
// 222.714 us; speedup vs baseline: 1.2067x; 1.2067x over previous
//
#include <hip/hip_runtime.h>
#include <math.h>

#define NT 1024
#define KSEL 100
#define NWAVE 16
#define HPAD 260   // per-wave hist stride: 16B-aligned, spreads copies across banks

// ws layout (floats):
//   Ct  [3][256][32]  at      0  (24576)   Ct[l][i][h] = sum_j w1[h,j]*W[j,i]
//   W0T [256][256]    at  24576  (65536)   W0T[c*256+i] = W0[i*256+c]
//   W1T [256][256]    at  90112  (65536)
//   W2T [256][128]    at 155648  (32768)   W2T[c*128+o] = W2[o*256+c]
#define WS_FLOATS 188416

// ---------- order-preserving float <-> uint key ----------
__device__ __forceinline__ unsigned fkey(float f) {
  unsigned u = __float_as_uint(f);
  return (u & 0x80000000u) ? ~u : (u | 0x80000000u);
}
__device__ __forceinline__ float unfkey(unsigned k) {
  return __uint_as_float((k & 0x80000000u) ? (k & 0x7FFFFFFFu) : ~k);
}

// recompute the path value s for element id e (e == p*256+i == JAX path index)
template<int NE>
__device__ __forceinline__ float recompute_s(int e, int b,
    const float* __restrict__ x, const float* __restrict__ wt,
    const float* __restrict__ Wprev, const int* path_col, const float* path_t)
{
  int i = e & 255;
  if (NE == 1) return x[b * 256 + i];
  int p = e >> 8;
  float w = wt ? wt[path_col[p] * 256 + i] : Wprev[i * 256 + path_col[p]];
  return tanhf(w * path_t[p]);
}

// ---------- exact top-100 radix select ----------
// NE==1 : 256 real elements (threads t<256), e = t  (others hold -inf)
// NE==25: 25600 elements, e = j*NT + t  (p = e>>8, i = e&255)
// prefix_p/krem_p/nsel_p/ntie_p must be pre-initialized (0,KSEL,0,0) before entry.
template<int NE>
__device__ __forceinline__ void topk_sel(
    const float (&sc)[25], int b, int t,
    const float* __restrict__ x, const float* __restrict__ wt,
    const float* __restrict__ Wprev,
    const int* path_col, const float* path_t,
    unsigned* hist,                      // [NWAVE*HPAD] per-wave copies
    int* sel_col, float* sel_s, float* sel_sc,
    unsigned* tieq,
    int* nsel_p, int* ntie_p, unsigned* prefix_p, int* krem_p)
{
  const int lane = t & 63;
  unsigned* histw = hist + (t >> 6) * HPAD;

  #pragma unroll
  for (int pass = 0; pass < 4; ++pass) {
    // zero own wave's copy (wave-private; entry/post-scan barrier orders this)
    {
      const int l4 = lane << 2;
      histw[l4] = 0u; histw[l4 + 1] = 0u; histw[l4 + 2] = 0u; histw[l4 + 3] = 0u;
    }
    const unsigned pref = *prefix_p;
    const int shift = 24 - 8 * pass;
    #pragma unroll
    for (int j = 0; j < NE; ++j) {
      unsigned key = fkey(sc[j]);
      bool cand = (pass == 0) || ((key >> (shift + 8)) == pref);
      if (cand) atomicAdd(&histw[(key >> shift) & 255u], 1u);
    }
    __syncthreads();
    if (t < 64) {
      const int l4 = t << 2;
      unsigned h0 = 0, h1 = 0, h2 = 0, h3 = 0;
      #pragma unroll
      for (int k = 0; k < NWAVE; ++k) {
        const uint4 v = *(const uint4*)&hist[k * HPAD + l4];
        h0 += v.x; h1 += v.y; h2 += v.z; h3 += v.w;
      }
      unsigned csum = h0 + h1 + h2 + h3;
      unsigned S = csum;                       // inclusive suffix over lane chunk sums
      #pragma unroll
      for (int off = 1; off < 64; off <<= 1) {
        unsigned v = __shfl_down(S, off, 64);
        if (t + off < 64) S += v;
      }
      unsigned tail = S - csum;
      unsigned s3 = tail + h3;
      unsigned s2 = s3 + h2;
      unsigned s1 = s2 + h1;
      unsigned s0v = s1 + h0;
      int krem = *krem_p;
      int ld = -1; unsigned sfx = 0, hd = 0;
      if      ((int)s3  >= krem) { ld = l4+3; sfx = s3;  hd = h3; }
      else if ((int)s2  >= krem) { ld = l4+2; sfx = s2;  hd = h2; }
      else if ((int)s1  >= krem) { ld = l4+1; sfx = s1;  hd = h1; }
      else if ((int)s0v >= krem) { ld = l4+0; sfx = s0v; hd = h0; }
      int gd = ld;
      #pragma unroll
      for (int off = 32; off >= 1; off >>= 1) {
        int v = __shfl_down(gd, off, 64);
        if (t + off < 64) gd = (v > gd) ? v : gd;
      }
      gd = __shfl(gd, 0, 64);
      if (ld == gd && ld >= 0) {               // unique owner lane
        *krem_p = krem - (int)(sfx - hd);
        *prefix_p = (pref << 8) | (unsigned)gd;
      }
    }
    __syncthreads();
  }

  const unsigned T = *prefix_p;                // exact key of the 100th-largest score

  #pragma unroll
  for (int j = 0; j < NE; ++j) {
    unsigned key = fkey(sc[j]);
    int e = (NE == 1) ? t : (j * NT + t);
    if (key > T) {
      int slot = atomicAdd(nsel_p, 1);
      sel_col[slot] = e & 255;
      sel_s[slot] = recompute_s<NE>(e, b, x, wt, Wprev, path_col, path_t);
      sel_sc[slot] = sc[j];
    } else if (key == T) {
      int tp = atomicAdd(ntie_p, 1);
      if (tp < 128) tieq[tp] = (unsigned)e;
    }
  }
  __syncthreads();

  if (t == 0) {                                // ties ascending by element id (JAX: lowest index)
    int m = *ntie_p; if (m > 128) m = 128;
    for (int a = 1; a < m; ++a) {
      unsigned v = tieq[a]; int c = a - 1;
      while (c >= 0 && tieq[c] > v) { tieq[c + 1] = tieq[c]; --c; }
      tieq[c + 1] = v;
    }
  }
  __syncthreads();

  const int G = *nsel_p;
  const int kt = KSEL - G;
  if (t < kt) {
    int e = (int)tieq[t];
    sel_col[G + t] = e & 255;
    sel_s[G + t] = recompute_s<NE>(e, b, x, wt, Wprev, path_col, path_t);
    sel_sc[G + t] = unfkey(T);
  }
  __syncthreads();
}

// ---------- kernel 1: Ct + transposed weights into ws ----------
__global__ void pqn_precompute(
    const float* __restrict__ W0, const float* __restrict__ W1, const float* __restrict__ W2,
    const float* __restrict__ s0w1, const float* __restrict__ s1w1, const float* __restrict__ s2w1,
    float* __restrict__ ws)
{
  int id = blockIdx.x * 256 + threadIdx.x;
  if (id < 24576) {
    int l = id >> 13, r = id & 8191;
    int i = r >> 5, h = r & 31;
    const float* W  = (l == 0) ? W0 : (l == 1) ? W1 : W2;
    const float* w1 = (l == 0) ? s0w1 : (l == 1) ? s1w1 : s2w1;
    const int Fout = (l == 2) ? 128 : 256;
    float acc = 0.f;
    for (int j = 0; j < Fout; ++j)
      acc = fmaf(w1[h * Fout + j], W[j * 256 + i], acc);
    ws[l * 8192 + i * 32 + h] = acc;
  } else if (id < 90112) {
    int k = id - 24576; int c = k >> 8, i = k & 255;
    ws[24576 + k] = W0[i * 256 + c];
  } else if (id < 155648) {
    int k = id - 90112; int c = k >> 8, i = k & 255;
    ws[90112 + k] = W1[i * 256 + c];
  } else if (id < 188416) {
    int k = id - 155648; int c = k >> 7, o = k & 127;
    ws[155648 + k] = W2[o * 256 + c];
  }
}

// ---------- kernel 2: one block per batch ----------
__global__ __launch_bounds__(NT, 4) void pqn_main(   // 4 waves/EU -> VGPR cap 128
    const float* __restrict__ x,
    const float* __restrict__ W0, const float* __restrict__ W1, const float* __restrict__ W2,
    const float* __restrict__ s0w1, const float* __restrict__ s1w1, const float* __restrict__ s2w1,
    const float* __restrict__ s0b1, const float* __restrict__ s1b1, const float* __restrict__ s2b1,
    const float* __restrict__ s0w2, const float* __restrict__ s1w2, const float* __restrict__ s2w2,
    const float* __restrict__ s0b2, const float* __restrict__ s1b2, const float* __restrict__ s2b2,
    const float* __restrict__ Ctg,   // null or [3][256][32]
    const float* __restrict__ Wtb,   // null or {W0T,W1T,W2T}
    float* __restrict__ out)
{
  __shared__ float Cl[8192];                    // fallback C (i-major), 32 KB
  __shared__ float A[256], Bc[256];
  __shared__ unsigned hist[NWAVE * HPAD];       // per-wave histogram copies
  __shared__ int   path_col[KSEL]; __shared__ float path_t[KSEL];
  __shared__ int   sel_col[KSEL];  __shared__ float sel_s[KSEL]; __shared__ float sel_sc[KSEL];
  __shared__ unsigned tieq[128];
  __shared__ int nsel_s, ntie_s, krem_s; __shared__ unsigned prefix_s;
  __shared__ int bz_s; __shared__ float b2_sh;
  __shared__ float wts[KSEL]; __shared__ float red[4];

  const int b = blockIdx.x;
  const int t = threadIdx.x;
  const bool useC  = (Ctg != nullptr);
  const bool useWT = (Wtb != nullptr);
  const float* W0T = useWT ? Wtb : nullptr;
  const float* W1T = useWT ? (Wtb + 65536) : nullptr;
  const float* W2T = useWT ? (Wtb + 131072) : nullptr;

  float sc[25];

  for (int l = 0; l < 3; ++l) {
    const float* w1 = (l == 0) ? s0w1 : (l == 1) ? s1w1 : s2w1;
    const float* b1 = (l == 0) ? s0b1 : (l == 1) ? s1b1 : s2b1;
    const float* w2 = (l == 0) ? s0w2 : (l == 1) ? s1w2 : s2w2;
    const float* b2 = (l == 0) ? s0b2 : (l == 1) ? s1b2 : s2b2;
    const float* Wl = (l == 0) ? W0 : (l == 1) ? W1 : W2;
    const float* Wprev = (l == 1) ? W0 : W1;
    const float* WTprev = (l == 1) ? W0T : W1T;
    const int Fout = (l == 2) ? 128 : 256;

    const float* ct;
    if (useC) {
      ct = Ctg + l * 8192;                     // i-major [256][32]
    } else {
      for (int id = t; id < 8192; id += NT) {
        int i = id >> 5, h = id & 31;
        float acc = 0.f;
        for (int j = 0; j < Fout; ++j) acc = fmaf(w1[h * Fout + j], Wl[j * 256 + i], acc);
        Cl[id] = acc;
      }
      ct = Cl;
      __syncthreads();
    }

    // scorer coefficients: score(s,i) = s * (s>0 ? A_i : B_i) + b2  (valid when b1==0)
    if (t < 256) {
      float a = 0.f, bn = 0.f;
      #pragma unroll
      for (int h = 0; h < 32; ++h) {
        float c = ct[t * 32 + h];
        float wc = w2[h] * c;
        if (c > 0.f) a += wc; else if (c < 0.f) bn += wc;
      }
      A[t] = a; Bc[t] = bn;
    }
    if (t == 0) {
      b2_sh = b2[0];
      int z = 1;
      for (int h = 0; h < 32; ++h) if (b1[h] != 0.f) z = 0;
      bz_s = z;
      prefix_s = 0u; krem_s = KSEL; nsel_s = 0; ntie_s = 0;   // select-state init folded in
    }
    __syncthreads();
    const bool  bz  = (bz_s != 0);
    const float b2v = b2_sh;

    if (l == 0) {
      float v = -INFINITY;
      if (t < 256) {
        float s = x[b * 256 + t];
        if (bz) v = s * (s > 0.f ? A[t] : Bc[t]) + b2v;
        else {
          v = b2v;
          for (int h = 0; h < 32; ++h)
            v += w2[h] * fmaxf(fmaf(s, ct[t * 32 + h], b1[h]), 0.f);
        }
      }
      sc[0] = v;
      topk_sel<1>(sc, b, t, x, nullptr, nullptr, path_col, path_t, hist,
                  sel_col, sel_s, sel_sc, tieq, &nsel_s, &ntie_s, &prefix_s, &krem_s);
    } else {
      // e = j*NT + t  ->  p = 4j + (t>>8)  (wave-uniform), i = t&255 (lane-consecutive, constant)
      const int i = t & 255;
      const int p0 = t >> 8;
      float wv[25], tv[25];
      if (useWT) {
        #pragma unroll
        for (int j = 0; j < 25; ++j) {
          int p = p0 + (j << 2);
          tv[j] = path_t[p];
          wv[j] = WTprev[(path_col[p] << 8) + i];   // 25 independent coalesced loads
        }
      } else {
        #pragma unroll
        for (int j = 0; j < 25; ++j) {
          int p = p0 + (j << 2);
          tv[j] = path_t[p];
          wv[j] = Wprev[i * 256 + path_col[p]];
        }
      }
      const float Ai = A[i], Bi = Bc[i];
      #pragma unroll
      for (int j = 0; j < 25; ++j) {
        float s = tanhf(wv[j] * tv[j]);
        float v;
        if (bz) v = s * (s > 0.f ? Ai : Bi) + b2v;
        else {
          v = b2v;
          for (int h = 0; h < 32; ++h)
            v += w2[h] * fmaxf(fmaf(s, ct[i * 32 + h], b1[h]), 0.f);
        }
        sc[j] = v;
      }
      topk_sel<25>(sc, b, t, x, WTprev, Wprev, path_col, path_t, hist,
                   sel_col, sel_s, sel_sc, tieq, &nsel_s, &ntie_s, &prefix_s, &krem_s);
    }

    if (l < 2) {
      if (t < KSEL) { path_col[t] = sel_col[t]; path_t[t] = sel_s[t]; }
      // visibility guaranteed by next layer's setup __syncthreads
    }
  }

  // ---------- epilogue: softmax over final scores, weighted column sum ----------
  {
    float v = (t < KSEL) ? sel_sc[t] : -INFINITY;
    if (t < 128) {
      #pragma unroll
      for (int off = 32; off >= 1; off >>= 1) v = fmaxf(v, __shfl_xor(v, off, 64));
      if ((t & 63) == 0) red[t >> 6] = v;
    }
    __syncthreads();
    const float m = fmaxf(red[0], red[1]);
    if (t < KSEL) wts[t] = expf(sel_sc[t] - m);
    __syncthreads();
    float sv = (t < KSEL) ? wts[t] : 0.f;
    if (t < 128) {
      #pragma unroll
      for (int off = 32; off >= 1; off >>= 1) sv += __shfl_xor(sv, off, 64);
      if ((t & 63) == 0) red[2 + (t >> 6)] = sv;
    }
    __syncthreads();
    const float ssum = red[2] + red[3];
    if (t < KSEL) wts[t] = wts[t] * sel_s[t] / ssum;   // coef_p = softmax_p * s_p
    __syncthreads();
    if (t < 128) {
      float acc = 0.f;
      if (useWT) {
        for (int p = 0; p < KSEL; ++p)
          acc = fmaf(W2T[sel_col[p] * 128 + t], wts[p], acc);   // coalesced
      } else {
        for (int p = 0; p < KSEL; ++p)
          acc = fmaf(W2[t * 256 + sel_col[p]], wts[p], acc);
      }
      out[b * 128 + t] = acc;
    }
  }
}

extern "C" void kernel_launch(void* const* d_in, const int* in_sizes, int n_in,
                              void* d_out, int out_size, void* d_ws, size_t ws_size,
                              hipStream_t stream) {
  const float* x    = (const float*)d_in[0];
  const float* W0   = (const float*)d_in[1];
  const float* s0w1 = (const float*)d_in[2];
  const float* s0b1 = (const float*)d_in[3];
  const float* s0w2 = (const float*)d_in[4];
  const float* s0b2 = (const float*)d_in[5];
  const float* W1   = (const float*)d_in[6];
  const float* s1w1 = (const float*)d_in[7];
  const float* s1b1 = (const float*)d_in[8];
  const float* s1w2 = (const float*)d_in[9];
  const float* s1b2 = (const float*)d_in[10];
  const float* W2   = (const float*)d_in[11];
  const float* s2w1 = (const float*)d_in[12];
  const float* s2b1 = (const float*)d_in[13];
  const float* s2w2 = (const float*)d_in[14];
  const float* s2b2 = (const float*)d_in[15];
  float* out = (float*)d_out;
  float* ws  = (float*)d_ws;

  const bool fullWs = ws_size >= (size_t)WS_FLOATS * sizeof(float);
  const bool cOnly  = !fullWs && ws_size >= (size_t)24576 * sizeof(float);

  const float* Ctg = nullptr; const float* Wtb = nullptr;
  if (fullWs) {
    pqn_precompute<<<736, 256, 0, stream>>>(W0, W1, W2, s0w1, s1w1, s2w1, ws);
    Ctg = ws; Wtb = ws + 24576;
  } else if (cOnly) {
    pqn_precompute<<<96, 256, 0, stream>>>(W0, W1, W2, s0w1, s1w1, s2w1, ws);
    Ctg = ws;
  }

  pqn_main<<<16, NT, 0, stream>>>(x, W0, W1, W2,
                                  s0w1, s1w1, s2w1,
                                  s0b1, s1b1, s2b1,
                                  s0w2, s1w2, s2w2,
                                  s0b2, s1b2, s2b2,
                                  Ctg, Wtb, out);
}

// Round 5
// 204.134 us; speedup vs baseline: 1.3166x; 1.0910x over previous
//
#include <hip/hip_runtime.h>
#include <math.h>

#define NT 1024
#define KSEL 100
#define NWAVE 16
#define HPAD 257   // per-wave hist stride in words; scalar scan reads, bank-spread copies

// ws layout (floats):
//   Ct  [3][32][256]  at      0  (24576)   Ct[l][h][i] = sum_j w1[h,j]*W[j,i]   (h-major!)
//   W0T [256][256]    at  24576  (65536)   W0T[c*256+i] = W0[i*256+c]
//   W1T [256][256]    at  90112  (65536)
//   W2T [256][128]    at 155648  (32768)   W2T[c*128+o] = W2[o*256+c]
#define WS_FLOATS 188416

// ---------- order-preserving float <-> uint key ----------
__device__ __forceinline__ unsigned fkey(float f) {
  unsigned u = __float_as_uint(f);
  return (u & 0x80000000u) ? ~u : (u | 0x80000000u);
}
__device__ __forceinline__ float unfkey(unsigned k) {
  return __uint_as_float((k & 0x80000000u) ? (k & 0x7FFFFFFFu) : ~k);
}

// recompute the path value s for element id e (e == p*256+i == JAX path index)
template<int NE>
__device__ __forceinline__ float recompute_s(int e, int b,
    const float* __restrict__ x, const float* __restrict__ wt,
    const float* __restrict__ Wprev, const int* path_col, const float* path_t)
{
  int i = e & 255;
  if (NE == 1) return x[b * 256 + i];
  int p = e >> 8;
  float w = wt ? wt[path_col[p] * 256 + i] : Wprev[i * 256 + path_col[p]];
  return tanhf(w * path_t[p]);
}

// ---------- exact top-100 radix select over cached keys ----------
// NE==1 : 256 real elements (threads t<256), e = t (others hold key of -inf)
// NE==25: 25600 elements, e = j*NT + t
// P0INLINE: caller already zeroed own-wave hist copy and did pass-0 atomics.
// prefix/krem/nsel/ntie must be pre-initialized (0,KSEL,0,0).
template<int NE, bool P0INLINE>
__device__ __forceinline__ void topk_sel(
    const unsigned (&key)[25], int b, int t,
    const float* __restrict__ x, const float* __restrict__ wt,
    const float* __restrict__ Wprev,
    const int* path_col, const float* path_t,
    unsigned* hist,                      // [NWAVE*HPAD] per-wave copies
    int* sel_col, float* sel_s, float* sel_sc,
    unsigned* tieq,
    int* nsel_p, int* ntie_p, unsigned* prefix_p, int* krem_p)
{
  const int lane = t & 63;
  unsigned* histw = hist + (t >> 6) * HPAD;

  #pragma unroll
  for (int pass = 0; pass < 4; ++pass) {
    if (!(P0INLINE && pass == 0)) {
      // zero own wave's copy (wave-private; prior post-decide barrier orders vs scan)
      const int l4 = lane << 2;
      histw[l4] = 0u; histw[l4 + 1] = 0u; histw[l4 + 2] = 0u; histw[l4 + 3] = 0u;
      const unsigned pref = *prefix_p;
      const int shift = 24 - 8 * pass;
      #pragma unroll
      for (int j = 0; j < NE; ++j) {
        bool cand = (pass == 0) || ((key[j] >> (shift + 8)) == pref);
        if (cand) atomicAdd(&histw[(key[j] >> shift) & 255u], 1u);
      }
    }
    __syncthreads();
    if (t < 64) {
      const int l4 = t << 2;
      unsigned h0 = 0, h1 = 0, h2 = 0, h3 = 0;
      #pragma unroll
      for (int k = 0; k < NWAVE; ++k) {
        const int base = k * HPAD + l4;
        h0 += hist[base]; h1 += hist[base + 1]; h2 += hist[base + 2]; h3 += hist[base + 3];
      }
      unsigned csum = h0 + h1 + h2 + h3;
      unsigned S = csum;                       // inclusive suffix over lane chunk sums
      #pragma unroll
      for (int off = 1; off < 64; off <<= 1) {
        unsigned v = __shfl_down(S, off, 64);
        if (t + off < 64) S += v;
      }
      unsigned tail = S - csum;
      unsigned s3 = tail + h3;
      unsigned s2 = s3 + h2;
      unsigned s1 = s2 + h1;
      unsigned s0v = s1 + h0;
      int krem = *krem_p;
      int ld = -1; unsigned sfx = 0, hd = 0;
      if      ((int)s3  >= krem) { ld = l4+3; sfx = s3;  hd = h3; }
      else if ((int)s2  >= krem) { ld = l4+2; sfx = s2;  hd = h2; }
      else if ((int)s1  >= krem) { ld = l4+1; sfx = s1;  hd = h1; }
      else if ((int)s0v >= krem) { ld = l4+0; sfx = s0v; hd = h0; }
      int gd = ld;
      #pragma unroll
      for (int off = 32; off >= 1; off >>= 1) {
        int v = __shfl_down(gd, off, 64);
        if (t + off < 64) gd = (v > gd) ? v : gd;
      }
      gd = __shfl(gd, 0, 64);
      if (ld == gd && ld >= 0) {               // unique owner lane
        *krem_p = krem - (int)(sfx - hd);
        unsigned pref = *prefix_p;
        *prefix_p = (pref << 8) | (unsigned)gd;
      }
    }
    __syncthreads();
  }

  const unsigned T = *prefix_p;                // exact key of the 100th-largest score

  #pragma unroll
  for (int j = 0; j < NE; ++j) {
    int e = (NE == 1) ? t : (j * NT + t);
    if (key[j] > T) {
      int slot = atomicAdd(nsel_p, 1);
      sel_col[slot] = e & 255;
      sel_s[slot] = recompute_s<NE>(e, b, x, wt, Wprev, path_col, path_t);
      sel_sc[slot] = unfkey(key[j]);
    } else if (key[j] == T) {
      int tp = atomicAdd(ntie_p, 1);
      if (tp < 128) tieq[tp] = (unsigned)e;
    }
  }
  __syncthreads();

  if (t == 0) {                                // ties ascending by element id (JAX: lowest index)
    int m = *ntie_p; if (m > 128) m = 128;
    for (int a = 1; a < m; ++a) {
      unsigned v = tieq[a]; int c = a - 1;
      while (c >= 0 && tieq[c] > v) { tieq[c + 1] = tieq[c]; --c; }
      tieq[c + 1] = v;
    }
  }
  __syncthreads();

  const int G = *nsel_p;
  const int kt = KSEL - G;
  if (t < kt) {
    int e = (int)tieq[t];
    sel_col[G + t] = e & 255;
    sel_s[G + t] = recompute_s<NE>(e, b, x, wt, Wprev, path_col, path_t);
    sel_sc[G + t] = unfkey(T);
  }
  __syncthreads();
}

// ---------- kernel 1: Ct (h-major) + transposed weights into ws ----------
__global__ void pqn_precompute(
    const float* __restrict__ W0, const float* __restrict__ W1, const float* __restrict__ W2,
    const float* __restrict__ s0w1, const float* __restrict__ s1w1, const float* __restrict__ s2w1,
    float* __restrict__ ws)
{
  int id = blockIdx.x * 256 + threadIdx.x;
  if (id < 24576) {
    int l = id >> 13, r = id & 8191;
    int h = r >> 8, i = r & 255;               // lanes consecutive in i -> coalesced
    const float* W  = (l == 0) ? W0 : (l == 1) ? W1 : W2;
    const float* w1 = (l == 0) ? s0w1 : (l == 1) ? s1w1 : s2w1;
    const int Fout = (l == 2) ? 128 : 256;
    float acc = 0.f;
    for (int j = 0; j < Fout; ++j)
      acc = fmaf(w1[h * Fout + j], W[j * 256 + i], acc);
    ws[l * 8192 + h * 256 + i] = acc;          // h-major
  } else if (id < 90112) {
    int k = id - 24576; int c = k >> 8, i = k & 255;
    ws[24576 + k] = W0[i * 256 + c];
  } else if (id < 155648) {
    int k = id - 90112; int c = k >> 8, i = k & 255;
    ws[90112 + k] = W1[i * 256 + c];
  } else if (id < 188416) {
    int k = id - 155648; int c = k >> 7, o = k & 127;
    ws[155648 + k] = W2[o * 256 + c];
  }
}

// ---------- kernel 2: one block per batch ----------
__global__ __launch_bounds__(NT, 4) void pqn_main(
    const float* __restrict__ x,
    const float* __restrict__ W0, const float* __restrict__ W1, const float* __restrict__ W2,
    const float* __restrict__ s0w1, const float* __restrict__ s1w1, const float* __restrict__ s2w1,
    const float* __restrict__ s0b1, const float* __restrict__ s1b1, const float* __restrict__ s2b1,
    const float* __restrict__ s0w2, const float* __restrict__ s1w2, const float* __restrict__ s2w2,
    const float* __restrict__ s0b2, const float* __restrict__ s1b2, const float* __restrict__ s2b2,
    const float* __restrict__ Ctg,   // null or [3][32][256] h-major
    const float* __restrict__ Wtb,   // null or {W0T,W1T,W2T}
    float* __restrict__ out)
{
  __shared__ float Cl[8192];                    // fallback C (h-major), 32 KB
  __shared__ float A[256], Bc[256];
  __shared__ unsigned hist[NWAVE * HPAD];       // per-wave histogram copies
  __shared__ int   path_col[KSEL]; __shared__ float path_t[KSEL];
  __shared__ int   sel_col[KSEL];  __shared__ float sel_s[KSEL]; __shared__ float sel_sc[KSEL];
  __shared__ unsigned tieq[128];
  __shared__ int nsel_s, ntie_s, krem_s; __shared__ unsigned prefix_s;
  __shared__ int bz_s; __shared__ float b2_sh;
  __shared__ float wts[KSEL]; __shared__ float red[4];

  const int b = blockIdx.x;
  const int t = threadIdx.x;
  const int lane = t & 63;
  const bool useC  = (Ctg != nullptr);
  const bool useWT = (Wtb != nullptr);
  const float* W0T = useWT ? Wtb : nullptr;
  const float* W1T = useWT ? (Wtb + 65536) : nullptr;
  const float* W2T = useWT ? (Wtb + 131072) : nullptr;

  unsigned key[25];

  for (int l = 0; l < 3; ++l) {
    const float* w1 = (l == 0) ? s0w1 : (l == 1) ? s1w1 : s2w1;
    const float* b1 = (l == 0) ? s0b1 : (l == 1) ? s1b1 : s2b1;
    const float* w2 = (l == 0) ? s0w2 : (l == 1) ? s1w2 : s2w2;
    const float* b2 = (l == 0) ? s0b2 : (l == 1) ? s1b2 : s2b2;
    const float* Wl = (l == 0) ? W0 : (l == 1) ? W1 : W2;
    const float* Wprev = (l == 1) ? W0 : W1;
    const float* WTprev = (l == 1) ? W0T : W1T;
    const int Fout = (l == 2) ? 128 : 256;

    const float* ct;
    if (useC) {
      ct = Ctg + l * 8192;                     // h-major [32][256]
    } else {
      for (int id = t; id < 8192; id += NT) {
        int h = id >> 8, i = id & 255;
        float acc = 0.f;
        for (int j = 0; j < Fout; ++j) acc = fmaf(w1[h * Fout + j], Wl[j * 256 + i], acc);
        Cl[id] = acc;
      }
      ct = Cl;
      __syncthreads();
    }

    // scorer coefficients: score(s,i) = s * (s>0 ? A_i : B_i) + b2  (valid when b1==0)
    if (t < 256) {
      float a = 0.f, bn = 0.f;
      #pragma unroll
      for (int h = 0; h < 32; ++h) {
        float c = ct[h * 256 + t];             // lane-consecutive, coalesced
        float wc = w2[h] * c;
        if (c > 0.f) a += wc; else if (c < 0.f) bn += wc;
      }
      A[t] = a; Bc[t] = bn;
    }
    if (t == 0) {
      b2_sh = b2[0];
      int z = 1;
      for (int h = 0; h < 32; ++h) if (b1[h] != 0.f) z = 0;
      bz_s = z;
      prefix_s = 0u; krem_s = KSEL; nsel_s = 0; ntie_s = 0;
    }
    __syncthreads();
    const bool  bz  = (bz_s != 0);
    const float b2v = b2_sh;

    if (l == 0) {
      float v = -INFINITY;
      if (t < 256) {
        float s = x[b * 256 + t];
        if (bz) v = s * (s > 0.f ? A[t] : Bc[t]) + b2v;
        else {
          v = b2v;
          for (int h = 0; h < 32; ++h)
            v += w2[h] * fmaxf(fmaf(s, ct[h * 256 + t], b1[h]), 0.f);
        }
      }
      key[0] = fkey(v);
      topk_sel<1, false>(key, b, t, x, nullptr, nullptr, path_col, path_t, hist,
                         sel_col, sel_s, sel_sc, tieq, &nsel_s, &ntie_s, &prefix_s, &krem_s);
    } else {
      // e = j*NT + t  ->  p = 4j + (t>>8) (wave-uniform), i = t&255 (lane-consecutive)
      const int i = t & 255;
      const int p0 = t >> 8;
      const float Ai = A[i], Bi = Bc[i];
      unsigned* histw = hist + (t >> 6) * HPAD;
      {  // zero own wave's pass-0 histogram copy (wave-private, no barrier needed)
        const int l4 = lane << 2;
        histw[l4] = 0u; histw[l4 + 1] = 0u; histw[l4 + 2] = 0u; histw[l4 + 3] = 0u;
      }
      // grouped: 9 independent loads, then 9 tanh+score (+ inline pass-0 atomics)
      #pragma unroll
      for (int g = 0; g < 25; g += 9) {
        const int gn = (25 - g) < 9 ? (25 - g) : 9;
        float wv[9], tv[9];
        #pragma unroll
        for (int jj = 0; jj < 9; ++jj) {
          if (jj < gn) {
            int p = p0 + ((g + jj) << 2);
            tv[jj] = path_t[p];
            wv[jj] = useWT ? WTprev[(path_col[p] << 8) + i]
                           : Wprev[i * 256 + path_col[p]];
          }
        }
        #pragma unroll
        for (int jj = 0; jj < 9; ++jj) {
          if (jj < gn) {
            float s = tanhf(wv[jj] * tv[jj]);
            float v;
            if (bz) v = s * (s > 0.f ? Ai : Bi) + b2v;
            else {
              v = b2v;
              for (int h = 0; h < 32; ++h)
                v += w2[h] * fmaxf(fmaf(s, ct[h * 256 + i], b1[h]), 0.f);
            }
            unsigned k = fkey(v);
            key[g + jj] = k;
            atomicAdd(&histw[k >> 24], 1u);     // inline radix pass 0
          }
        }
      }
      topk_sel<25, true>(key, b, t, x, WTprev, Wprev, path_col, path_t, hist,
                         sel_col, sel_s, sel_sc, tieq, &nsel_s, &ntie_s, &prefix_s, &krem_s);
    }

    if (l < 2) {
      if (t < KSEL) { path_col[t] = sel_col[t]; path_t[t] = sel_s[t]; }
      // visibility guaranteed by next layer's setup __syncthreads
    }
  }

  // ---------- epilogue: softmax over final scores, weighted column sum ----------
  {
    float v = (t < KSEL) ? sel_sc[t] : -INFINITY;
    if (t < 128) {
      #pragma unroll
      for (int off = 32; off >= 1; off >>= 1) v = fmaxf(v, __shfl_xor(v, off, 64));
      if ((t & 63) == 0) red[t >> 6] = v;
    }
    __syncthreads();
    const float m = fmaxf(red[0], red[1]);
    if (t < KSEL) wts[t] = expf(sel_sc[t] - m);
    __syncthreads();
    float sv = (t < KSEL) ? wts[t] : 0.f;
    if (t < 128) {
      #pragma unroll
      for (int off = 32; off >= 1; off >>= 1) sv += __shfl_xor(sv, off, 64);
      if ((t & 63) == 0) red[2 + (t >> 6)] = sv;
    }
    __syncthreads();
    const float ssum = red[2] + red[3];
    if (t < KSEL) wts[t] = wts[t] * sel_s[t] / ssum;   // coef_p = softmax_p * s_p
    __syncthreads();
    if (t < 128) {
      float acc = 0.f;
      if (useWT) {
        for (int p = 0; p < KSEL; ++p)
          acc = fmaf(W2T[sel_col[p] * 128 + t], wts[p], acc);   // coalesced
      } else {
        for (int p = 0; p < KSEL; ++p)
          acc = fmaf(W2[t * 256 + sel_col[p]], wts[p], acc);
      }
      out[b * 128 + t] = acc;
    }
  }
}

extern "C" void kernel_launch(void* const* d_in, const int* in_sizes, int n_in,
                              void* d_out, int out_size, void* d_ws, size_t ws_size,
                              hipStream_t stream) {
  const float* x    = (const float*)d_in[0];
  const float* W0   = (const float*)d_in[1];
  const float* s0w1 = (const float*)d_in[2];
  const float* s0b1 = (const float*)d_in[3];
  const float* s0w2 = (const float*)d_in[4];
  const float* s0b2 = (const float*)d_in[5];
  const float* W1   = (const float*)d_in[6];
  const float* s1w1 = (const float*)d_in[7];
  const float* s1b1 = (const float*)d_in[8];
  const float* s1w2 = (const float*)d_in[9];
  const float* s1b2 = (const float*)d_in[10];
  const float* W2   = (const float*)d_in[11];
  const float* s2w1 = (const float*)d_in[12];
  const float* s2b1 = (const float*)d_in[13];
  const float* s2w2 = (const float*)d_in[14];
  const float* s2b2 = (const float*)d_in[15];
  float* out = (float*)d_out;
  float* ws  = (float*)d_ws;

  const bool fullWs = ws_size >= (size_t)WS_FLOATS * sizeof(float);
  const bool cOnly  = !fullWs && ws_size >= (size_t)24576 * sizeof(float);

  const float* Ctg = nullptr; const float* Wtb = nullptr;
  if (fullWs) {
    pqn_precompute<<<736, 256, 0, stream>>>(W0, W1, W2, s0w1, s1w1, s2w1, ws);
    Ctg = ws; Wtb = ws + 24576;
  } else if (cOnly) {
    pqn_precompute<<<96, 256, 0, stream>>>(W0, W1, W2, s0w1, s1w1, s2w1, ws);
    Ctg = ws;
  }

  pqn_main<<<16, NT, 0, stream>>>(x, W0, W1, W2,
                                  s0w1, s1w1, s2w1,
                                  s0b1, s1b1, s2b1,
                                  s0w2, s1w2, s2w2,
                                  s0b2, s1b2, s2b2,
                                  Ctg, Wtb, out);
}